// Round 1
// baseline (431.665 us; speedup 1.0000x reference)
//
#include <hip/hip_runtime.h>

#define CDIM 768
#define SDIM 4096
#define SV (SDIM / 4) // row length in float4

// out[b,c] = bias[c] + sum_k X[b,k] * W[c,k]   (one wave per output element)
__global__ __launch_bounds__(256) void small_gemm_kernel(
    const float* __restrict__ X, const float* __restrict__ W,
    const float* __restrict__ bias, float* __restrict__ out,
    int Cn, int K)
{
    int gid  = blockIdx.x * blockDim.x + threadIdx.x;
    int wid  = gid >> 6;
    int lane = threadIdx.x & 63;
    int total = 16 * Cn;
    if (wid >= total) return;
    int b = wid / Cn;
    int c = wid - b * Cn;
    const float* x = X + (size_t)b * K;
    const float* w = W + (size_t)c * K;
    float acc = 0.f;
    for (int k = lane * 4; k < K; k += 256) {
        float4 xv = *(const float4*)(x + k);
        float4 wv = *(const float4*)(w + k);
        acc += xv.x * wv.x + xv.y * wv.y + xv.z * wv.z + xv.w * wv.w;
    }
#pragma unroll
    for (int m = 32; m; m >>= 1) acc += __shfl_xor(acc, m, 64);
    if (lane == 0) out[wid] = acc + bias[c];
}

// One wave per (b, 64-s tile). Lane = (cg<<4)|si: si picks a float4 s-column,
// cg picks a 192-wide c-stripe. Pass 1: sum/sumsq; xor-reduce over cg bits;
// Pass 2: re-read (L2/L3 warm), normalize, store.
__global__ __launch_bounds__(64) void fused_add_ln_kernel(
    const float* __restrict__ sp, const float* __restrict__ proj,
    const float* __restrict__ gamma, const float* __restrict__ beta,
    float* __restrict__ out)
{
    __shared__ float s_proj[CDIM], s_gamma[CDIM], s_beta[CDIM];
    const int b    = blockIdx.y;
    const int s0   = blockIdx.x * 64;
    const int lane = threadIdx.x;
    for (int i = lane; i < CDIM; i += 64) {
        s_proj[i]  = proj[b * CDIM + i];
        s_gamma[i] = gamma[i];
        s_beta[i]  = beta[i];
    }
    __syncthreads();

    const int si = lane & 15;
    const int cg = lane >> 4;
    const int c0 = cg * (CDIM / 4);
    const int c1 = c0 + (CDIM / 4);

    const float4* spv  = (const float4*)(sp  + (size_t)b * CDIM * SDIM + s0);
    float4*       outv = (float4*)      (out + (size_t)b * CDIM * SDIM + s0);

    float sx = 0, sy = 0, sz = 0, sw = 0;
    float qx = 0, qy = 0, qz = 0, qw = 0;
    for (int c = c0; c < c1; ++c) {
        float4 t = spv[(size_t)c * SV + si];
        float  p = s_proj[c];
        t.x += p; t.y += p; t.z += p; t.w += p;
        sx += t.x; sy += t.y; sz += t.z; sw += t.w;
        qx += t.x * t.x; qy += t.y * t.y; qz += t.z * t.z; qw += t.w * t.w;
    }
#pragma unroll
    for (int m = 16; m <= 32; m <<= 1) {
        sx += __shfl_xor(sx, m, 64); sy += __shfl_xor(sy, m, 64);
        sz += __shfl_xor(sz, m, 64); sw += __shfl_xor(sw, m, 64);
        qx += __shfl_xor(qx, m, 64); qy += __shfl_xor(qy, m, 64);
        qz += __shfl_xor(qz, m, 64); qw += __shfl_xor(qw, m, 64);
    }
    const float inv = 1.f / CDIM;
    const float mux = sx * inv, muy = sy * inv, muz = sz * inv, muw = sw * inv;
    const float rx = rsqrtf(qx * inv - mux * mux + 1e-5f);
    const float ry = rsqrtf(qy * inv - muy * muy + 1e-5f);
    const float rz = rsqrtf(qz * inv - muz * muz + 1e-5f);
    const float rw = rsqrtf(qw * inv - muw * muw + 1e-5f);

    for (int c = c0; c < c1; ++c) {
        float4 t = spv[(size_t)c * SV + si];
        float  p  = s_proj[c];
        float  g  = s_gamma[c];
        float  be = s_beta[c];
        float4 y;
        y.x = (t.x + p - mux) * rx * g + be;
        y.y = (t.y + p - muy) * ry * g + be;
        y.z = (t.z + p - muz) * rz * g + be;
        y.w = (t.w + p - muw) * rw * g + be;
        outv[(size_t)c * SV + si] = y;
    }
}

extern "C" void kernel_launch(void* const* d_in, const int* in_sizes, int n_in,
                              void* d_out, int out_size, void* d_ws, size_t ws_size,
                              hipStream_t stream) {
    const float* sp           = (const float*)d_in[0];
    const float* conditioning = (const float*)d_in[1];
    const float* w_cond       = (const float*)d_in[2];
    const float* b_cond       = (const float*)d_in[3];
    const float* in_proj_w    = (const float*)d_in[4];
    const float* in_proj_b    = (const float*)d_in[5];
    const float* attn_out_w   = (const float*)d_in[6];
    const float* attn_out_b   = (const float*)d_in[7];
    const float* w_out        = (const float*)d_in[8];
    const float* b_out        = (const float*)d_in[9];
    const float* ln_gamma     = (const float*)d_in[10];
    const float* ln_beta      = (const float*)d_in[11];
    float* out = (float*)d_out;
    float* ws  = (float*)d_ws;

    float* cond = ws;            // 16*768
    float* v    = ws + 12288;    // 16*768
    float* attn = ws + 24576;    // 16*768
    float* proj = ws + 36864;    // 16*768

    const int gemm_blocks = (16 * CDIM * 64) / 256; // 3072 blocks, wave per output
    small_gemm_kernel<<<gemm_blocks, 256, 0, stream>>>(
        conditioning, w_cond, b_cond, cond, CDIM, 1024);
    small_gemm_kernel<<<gemm_blocks, 256, 0, stream>>>(
        cond, in_proj_w + 2 * CDIM * CDIM, in_proj_b + 2 * CDIM, v, CDIM, CDIM);
    small_gemm_kernel<<<gemm_blocks, 256, 0, stream>>>(
        v, attn_out_w, attn_out_b, attn, CDIM, CDIM);
    small_gemm_kernel<<<gemm_blocks, 256, 0, stream>>>(
        attn, w_out, b_out, proj, CDIM, CDIM);

    dim3 grid(SDIM / 64, 16);
    fused_add_ln_kernel<<<grid, 64, 0, stream>>>(sp, proj, ln_gamma, ln_beta, out);
}

// Round 3
// 421.389 us; speedup vs baseline: 1.0244x; 1.0244x over previous
//
#include <hip/hip_runtime.h>

#define CDIM 768
#define SDIM 4096
#define SV (SDIM / 4) // row length in float4

typedef float nfloat4 __attribute__((ext_vector_type(4))); // native vec for nontemporal builtin

// out[b,c] = bias[c] + sum_k X[b,k] * W[c,k]   (one wave per output element)
__global__ __launch_bounds__(256) void small_gemm_kernel(
    const float* __restrict__ X, const float* __restrict__ W,
    const float* __restrict__ bias, float* __restrict__ out,
    int Cn, int K)
{
    int gid  = blockIdx.x * blockDim.x + threadIdx.x;
    int wid  = gid >> 6;
    int lane = threadIdx.x & 63;
    int total = 16 * Cn;
    if (wid >= total) return;
    int b = wid / Cn;
    int c = wid - b * Cn;
    const float* x = X + (size_t)b * K;
    const float* w = W + (size_t)c * K;
    float acc = 0.f;
    for (int k = lane * 4; k < K; k += 256) {
        float4 xv = *(const float4*)(x + k);
        float4 wv = *(const float4*)(w + k);
        acc += xv.x * wv.x + xv.y * wv.y + xv.z * wv.z + xv.w * wv.w;
    }
#pragma unroll
    for (int m = 32; m; m >>= 1) acc += __shfl_xor(acc, m, 64);
    if (lane == 0) out[wid] = acc + bias[c];
}

// Block = 256 threads per (b, 64-s tile). thread t: si = t&15 (one float4
// s-column), cg = t>>4 (0..15), c-stripe of 48. Pass 1: per-thread partial
// sum/sumsq -> LDS [cg][si] -> 16 reducer threads -> mu/rs per column.
// Pass 2: re-read (cache-warm), normalize, nontemporal store.
__global__ __launch_bounds__(256) void fused_add_ln_kernel(
    const float* __restrict__ sp, const float* __restrict__ proj,
    const float* __restrict__ gamma, const float* __restrict__ beta,
    float* __restrict__ out)
{
    __shared__ float s_proj[CDIM], s_gamma[CDIM], s_beta[CDIM];
    __shared__ float4 red_s[16][16];
    __shared__ float4 red_q[16][16];
    __shared__ float4 s_mu[16];
    __shared__ float4 s_rs[16];

    const int b  = blockIdx.y;
    const int s0 = blockIdx.x * 64;
    const int t  = threadIdx.x;
    for (int i = t; i < CDIM; i += 256) {
        s_proj[i]  = proj[b * CDIM + i];
        s_gamma[i] = gamma[i];
        s_beta[i]  = beta[i];
    }
    __syncthreads();

    const int si = t & 15;
    const int cg = t >> 4;
    const int c0 = cg * (CDIM / 16);       // 48 c's per thread
    const int c1 = c0 + (CDIM / 16);

    const float4* spv  = (const float4*)(sp  + (size_t)b * CDIM * SDIM + s0);
    nfloat4*      outv = (nfloat4*)     (out + (size_t)b * CDIM * SDIM + s0);

    float sx = 0, sy = 0, sz = 0, sw = 0;
    float qx = 0, qy = 0, qz = 0, qw = 0;
#pragma unroll 4
    for (int c = c0; c < c1; ++c) {
        float4 v = spv[(size_t)c * SV + si];
        float  p = s_proj[c];
        v.x += p; v.y += p; v.z += p; v.w += p;
        sx += v.x; sy += v.y; sz += v.z; sw += v.w;
        qx += v.x * v.x; qy += v.y * v.y; qz += v.z * v.z; qw += v.w * v.w;
    }
    red_s[cg][si] = make_float4(sx, sy, sz, sw);
    red_q[cg][si] = make_float4(qx, qy, qz, qw);
    __syncthreads();

    if (t < 16) {
        float4 S = make_float4(0, 0, 0, 0), Q = make_float4(0, 0, 0, 0);
#pragma unroll
        for (int g = 0; g < 16; ++g) {
            float4 a = red_s[g][t], q = red_q[g][t];
            S.x += a.x; S.y += a.y; S.z += a.z; S.w += a.w;
            Q.x += q.x; Q.y += q.y; Q.z += q.z; Q.w += q.w;
        }
        const float inv = 1.f / CDIM;
        float4 mu = make_float4(S.x * inv, S.y * inv, S.z * inv, S.w * inv);
        float4 rs;
        rs.x = rsqrtf(Q.x * inv - mu.x * mu.x + 1e-5f);
        rs.y = rsqrtf(Q.y * inv - mu.y * mu.y + 1e-5f);
        rs.z = rsqrtf(Q.z * inv - mu.z * mu.z + 1e-5f);
        rs.w = rsqrtf(Q.w * inv - mu.w * mu.w + 1e-5f);
        s_mu[t] = mu;
        s_rs[t] = rs;
    }
    __syncthreads();

    const float4 mu = s_mu[si];
    const float4 rs = s_rs[si];
#pragma unroll 4
    for (int c = c0; c < c1; ++c) {
        float4 v = spv[(size_t)c * SV + si];
        float  p  = s_proj[c];
        float  g  = s_gamma[c];
        float  be = s_beta[c];
        nfloat4 y;
        y.x = (v.x + p - mu.x) * rs.x * g + be;
        y.y = (v.y + p - mu.y) * rs.y * g + be;
        y.z = (v.z + p - mu.z) * rs.z * g + be;
        y.w = (v.w + p - mu.w) * rs.w * g + be;
        __builtin_nontemporal_store(y, &outv[(size_t)c * SV + si]);
    }
}

extern "C" void kernel_launch(void* const* d_in, const int* in_sizes, int n_in,
                              void* d_out, int out_size, void* d_ws, size_t ws_size,
                              hipStream_t stream) {
    const float* sp           = (const float*)d_in[0];
    const float* conditioning = (const float*)d_in[1];
    const float* w_cond       = (const float*)d_in[2];
    const float* b_cond       = (const float*)d_in[3];
    const float* in_proj_w    = (const float*)d_in[4];
    const float* in_proj_b    = (const float*)d_in[5];
    const float* attn_out_w   = (const float*)d_in[6];
    const float* attn_out_b   = (const float*)d_in[7];
    const float* w_out        = (const float*)d_in[8];
    const float* b_out        = (const float*)d_in[9];
    const float* ln_gamma     = (const float*)d_in[10];
    const float* ln_beta      = (const float*)d_in[11];
    float* out = (float*)d_out;
    float* ws  = (float*)d_ws;

    float* cond = ws;            // 16*768
    float* v    = ws + 12288;    // 16*768
    float* attn = ws + 24576;    // 16*768
    float* proj = ws + 36864;    // 16*768

    const int gemm_blocks = (16 * CDIM * 64) / 256; // wave per output
    small_gemm_kernel<<<gemm_blocks, 256, 0, stream>>>(
        conditioning, w_cond, b_cond, cond, CDIM, 1024);
    small_gemm_kernel<<<gemm_blocks, 256, 0, stream>>>(
        cond, in_proj_w + 2 * CDIM * CDIM, in_proj_b + 2 * CDIM, v, CDIM, CDIM);
    small_gemm_kernel<<<gemm_blocks, 256, 0, stream>>>(
        v, attn_out_w, attn_out_b, attn, CDIM, CDIM);
    small_gemm_kernel<<<gemm_blocks, 256, 0, stream>>>(
        attn, w_out, b_out, proj, CDIM, CDIM);

    dim3 grid(SDIM / 64, 16);
    fused_add_ln_kernel<<<grid, 256, 0, stream>>>(sp, proj, ln_gamma, ln_beta, out);
}